// Round 9
// baseline (160.201 us; speedup 1.0000x reference)
//
#include <hip/hip_runtime.h>
#include <hip/hip_bf16.h>

// NT-Xent (SimCLR) loss, B=4096, D=256, N=8192, T=0.5.
// loss = [ sum_i log(sum_{j!=i} exp(sim_ij * 2)) - 4 * sum_{i<B} pos_i ] / N
// sim symmetric: upper-triangle tiles only. STRIP-MINED for L2-traffic
// reduction (r8 post-mortem: all prior structures were L2-BW-bound at
// ~532 MB): block = (row-strip of 128 rows, chunk of <=8 column tiles of
// 128). A-strip staged ONCE per block into LDS (64 KB, fragment order,
// linear DMA); B streamed barrier-free from L2 in fragment order. Traffic
// ~151 MB (3.5x cut). 288 blocks = 8*36, 4 waves, 2 blocks/CU.

constexpr int BB = 4096;                 // batch
constexpr int NN = 8192;                 // 2*batch
constexpr int DD = 256;                  // feature dim
constexpr int TS = 128;                  // tile edge
constexpr int NT = NN / TS;              // 64 tile rows/cols
constexpr int CW = 8;                    // column tiles per block chunk
constexpr int NBLK = 288;                // sum over rt of ceil((NT-rt)/CW)
constexpr int KSTEPS = DD / 16;          // 16 MFMA k-steps

typedef _Float16 half4v __attribute__((ext_vector_type(4)));
typedef _Float16 half8v __attribute__((ext_vector_type(8)));
typedef float floatx16 __attribute__((ext_vector_type(16)));

// ---------------- Kernel 1: normalize -> fragment-ordered f16 (r8 verbatim) -
// Zf granule (g*16+ks)*64 + lm + 32*lh holds halfs [16ks+8lh, +8) of row
// 32g+lm. A wave's fragment load = 1 KB contiguous.
__global__ __launch_bounds__(256) void nt_normalize(
    const float* __restrict__ zi, const float* __restrict__ zj,
    _Float16* __restrict__ Zf, float* __restrict__ pos,
    float* __restrict__ rowsum)
{
    __shared__ _Float16 sZ[2][16 * 64 * 8];   // 2 groups x 1024 granules = 32 KB
    const int tid = threadIdx.x;
    const int pr  = tid >> 3;     // row within group, 0..31
    const int sub = tid & 7;      // 8 threads per row
    const int p   = blockIdx.x * 32 + pr;     // pair index, < BB

    if (blockIdx.x < 32) rowsum[blockIdx.x * 256 + tid] = 0.f;

    const float4* ai = (const float4*)(zi + (size_t)p * DD);
    const float4* bj = (const float4*)(zj + (size_t)p * DD);
    float4 av[8], bv[8];
    float ssi = 0.f, ssj = 0.f, dd = 0.f;
#pragma unroll
    for (int t = 0; t < 8; ++t) {
        av[t] = ai[sub + 8 * t];
        bv[t] = bj[sub + 8 * t];
        ssi += av[t].x*av[t].x + av[t].y*av[t].y + av[t].z*av[t].z + av[t].w*av[t].w;
        ssj += bv[t].x*bv[t].x + bv[t].y*bv[t].y + bv[t].z*bv[t].z + bv[t].w*bv[t].w;
        dd  += av[t].x*bv[t].x + av[t].y*bv[t].y + av[t].z*bv[t].z + av[t].w*bv[t].w;
    }
#pragma unroll
    for (int off = 1; off < 8; off <<= 1) {
        ssi += __shfl_xor(ssi, off);
        ssj += __shfl_xor(ssj, off);
        dd  += __shfl_xor(dd,  off);
    }
    const float invi = rsqrtf(ssi);
    const float invj = rsqrtf(ssj);
    if (sub == 0) pos[p] = dd * invi * invj;

#pragma unroll
    for (int t = 0; t < 8; ++t) {
        const int gi = (2 * t + (sub >> 2)) * 64 + pr + 32 * ((sub >> 1) & 1);
        const int wo = 4 * (sub & 1);
        half4v hi, hj;
        hi.x = (_Float16)(av[t].x * invi); hi.y = (_Float16)(av[t].y * invi);
        hi.z = (_Float16)(av[t].z * invi); hi.w = (_Float16)(av[t].w * invi);
        hj.x = (_Float16)(bv[t].x * invj); hj.y = (_Float16)(bv[t].y * invj);
        hj.z = (_Float16)(bv[t].z * invj); hj.w = (_Float16)(bv[t].w * invj);
        *(half4v*)&sZ[0][gi * 8 + wo] = hi;
        *(half4v*)&sZ[1][gi * 8 + wo] = hj;
    }
    __syncthreads();

    float4* Zf4 = (float4*)Zf;
    const float4* s0 = (const float4*)sZ[0];
    const float4* s1 = (const float4*)sZ[1];
    const size_t gbi = (size_t)blockIdx.x * 1024;
    const size_t gbj = (size_t)(128 + blockIdx.x) * 1024;
#pragma unroll
    for (int it = 0; it < 4; ++it) {
        Zf4[gbi + tid + it * 256] = s0[tid + it * 256];
        Zf4[gbj + tid + it * 256] = s1[tid + it * 256];
    }
}

// DPP half-wave reduce: lane31 = sum(lanes 0..31), lane63 = sum(lanes 32..63).
__device__ __forceinline__ float half_sums(float x) {
    int t;
    t = __builtin_amdgcn_update_dpp(0, __builtin_bit_cast(int, x), 0x111, 0xf, 0xf, false);
    x += __builtin_bit_cast(float, t);
    t = __builtin_amdgcn_update_dpp(0, __builtin_bit_cast(int, x), 0x112, 0xf, 0xf, false);
    x += __builtin_bit_cast(float, t);
    t = __builtin_amdgcn_update_dpp(0, __builtin_bit_cast(int, x), 0x114, 0xf, 0xf, false);
    x += __builtin_bit_cast(float, t);
    t = __builtin_amdgcn_update_dpp(0, __builtin_bit_cast(int, x), 0x118, 0xf, 0xf, false);
    x += __builtin_bit_cast(float, t);
    t = __builtin_amdgcn_update_dpp(0, __builtin_bit_cast(int, x), 0x142, 0xa, 0xf, false);
    x += __builtin_bit_cast(float, t);
    return x;
}

// ---------------- Kernel 2: strip-mined upper-tri sim + exp + row/col sums --
// Grid: 288 blocks x 256 thr (4 waves). Block = (rt, ct0..ct0+ncw-1).
// A-strip (4 groups x 16 KB, fragment order) staged once in LDS.
// Job = 64 output cols (2 col-groups) of one tile; wave w does jobs w, w+4,..
// Per job: k-loop 16 x {4 ds_read_b128 (A) + 2 coalesced global (B) + 8 MFMA},
// acc[4][2] covers 128 rows x 64 cols. No k-loop barriers.
__global__ __launch_bounds__(256, 2) void nt_simexp(
    const _Float16* __restrict__ Zf, float* __restrict__ rowsum)
{
    __shared__ alignas(16) _Float16 sA[4 * 16 * 64 * 8];   // 64 KB
    __shared__ float rowaccA[TS];                          // 512 B

    // Bijective XCD swizzle (288 % 8 == 0).
    const int bid = (blockIdx.x & 7) * (NBLK / 8) + (blockIdx.x >> 3);

    // Map bid -> (rt, chunk). Strips rt=0..63, strip rt has ceil((64-rt)/8)
    // chunks. Scalar loop, <=64 iterations, shifts only.
    int rt = 0, rem = bid;
    while (true) {
        const int nch = (NT - rt + CW - 1) >> 3;
        if (rem < nch) break;
        rem -= nch; ++rt;
    }
    const int ct0 = rt + rem * CW;
    const int ncw = min(CW, NT - ct0);
    const int njobs = 2 * ncw;

    const int tid = threadIdx.x;
    const int wave = tid >> 6;
    const int lane = tid & 63;
    const int lm = lane & 31;
    const int lh = lane >> 5;

    // Stage A-strip: wave w stages group w (16 calls of 1 KB). Linear source
    // (Zf fragment order), linear dest; lane term lane*16B on both sides.
    {
        const _Float16* src = Zf + ((size_t)(rt * 4 + wave) * 1024 + lane) * 8;
        _Float16* dst = sA + (size_t)wave * 16 * 64 * 8;   // wave-uniform base
#pragma unroll
        for (int ks = 0; ks < 16; ++ks) {
            __builtin_amdgcn_global_load_lds(
                (const __attribute__((address_space(1))) unsigned int*)(src + ks * 64 * 8),
                (__attribute__((address_space(3))) unsigned int*)(dst + ks * 64 * 8),
                16, 0, 0);
        }
    }
    if (tid < TS) rowaccA[tid] = 0.f;
    __syncthreads();                 // DMA drained (implicit vmcnt), zero done

    const half8v* sAf = (const half8v*)sA;
    const float KEXP = 2.0f * 1.44269504088896340736f;

    for (int j = wave; j < njobs; j += 4) {
        const int ct = ct0 + (j >> 1);
        const int jit = j & 1;               // 64-col half within the tile
        const bool dj = (ct == rt);
        const int cb = ct * TS + jit * 64;   // global col base of this job

        // B fragment streams (2 col-groups), r8-verified coalesced layout.
        const half8v* pb0 = (const half8v*)Zf + ((size_t)(cb >> 5)) * 1024 + lane;
        const half8v* pb1 = pb0 + 1024;

        floatx16 acc[4][2];
#pragma unroll
        for (int g = 0; g < 4; ++g)
#pragma unroll
            for (int c = 0; c < 2; ++c)
#pragma unroll
                for (int r = 0; r < 16; ++r) acc[g][c][r] = 0.f;

        half8v fb0 = pb0[0], fb1 = pb1[0];
#pragma unroll
        for (int ks = 0; ks < KSTEPS; ++ks) {
            half8v nb0 = fb0, nb1 = fb1;
            if (ks + 1 < KSTEPS) {
                nb0 = pb0[(ks + 1) * 64];
                nb1 = pb1[(ks + 1) * 64];
            }
            half8v fa0 = sAf[(0 * 16 + ks) * 64 + lane];
            half8v fa1 = sAf[(1 * 16 + ks) * 64 + lane];
            half8v fa2 = sAf[(2 * 16 + ks) * 64 + lane];
            half8v fa3 = sAf[(3 * 16 + ks) * 64 + lane];
            acc[0][0] = __builtin_amdgcn_mfma_f32_32x32x16_f16(fa0, fb0, acc[0][0], 0, 0, 0);
            acc[0][1] = __builtin_amdgcn_mfma_f32_32x32x16_f16(fa0, fb1, acc[0][1], 0, 0, 0);
            acc[1][0] = __builtin_amdgcn_mfma_f32_32x32x16_f16(fa1, fb0, acc[1][0], 0, 0, 0);
            acc[1][1] = __builtin_amdgcn_mfma_f32_32x32x16_f16(fa1, fb1, acc[1][1], 0, 0, 0);
            acc[2][0] = __builtin_amdgcn_mfma_f32_32x32x16_f16(fa2, fb0, acc[2][0], 0, 0, 0);
            acc[2][1] = __builtin_amdgcn_mfma_f32_32x32x16_f16(fa2, fb1, acc[2][1], 0, 0, 0);
            acc[3][0] = __builtin_amdgcn_mfma_f32_32x32x16_f16(fa3, fb0, acc[3][0], 0, 0, 0);
            acc[3][1] = __builtin_amdgcn_mfma_f32_32x32x16_f16(fa3, fb1, acc[3][1], 0, 0, 0);
            fb0 = nb0; fb1 = nb1;
        }

        // Epilogue (r8-verified math, re-indexed). Element (g, tc, r):
        // strip row = 32g + mrow, tile col = jit*64 + tc*32 + lm.
        float ebs0 = 0.f, ebs1 = 0.f;
#pragma unroll
        for (int g = 0; g < 4; ++g) {
#pragma unroll
            for (int r = 0; r < 16; ++r) {
                const int mrow = (r & 3) + 8 * (r >> 2) + 4 * lh;
                float e0 = __builtin_amdgcn_exp2f(acc[g][0][r] * KEXP);
                float e1 = __builtin_amdgcn_exp2f(acc[g][1][r] * KEXP);
                if (dj) {   // mask global diagonal (row == col)
                    const int rowInTile = 32 * g + mrow;
                    if (rowInTile == jit * 64 + lm)      e0 = 0.f;
                    if (rowInTile == jit * 64 + 32 + lm) e1 = 0.f;
                }
                ebs0 += e0; ebs1 += e1;
                if (!dj) {   // A-side (strip-row) sums via DPP reduce
                    float s2 = half_sums(e0 + e1);       // lanes 31/63
                    if (lm == 31)
                        atomicAdd(&rowaccA[32 * g + mrow], s2);   // ds_add
                }
            }
        }
        // B-side (col) sums: wave covers all 128 strip rows -> complete here.
        ebs0 += __shfl_xor(ebs0, 32);
        ebs1 += __shfl_xor(ebs1, 32);
        if (lane < 32) {
            atomicAdd(&rowsum[cb + lm], ebs0);
            atomicAdd(&rowsum[cb + 32 + lm], ebs1);
        }
    }

    __syncthreads();
    if (tid < TS) atomicAdd(&rowsum[rt * TS + tid], rowaccA[tid]);
}

// ---------------- Kernel 3: finalize ----------------------------------------
__global__ __launch_bounds__(256) void nt_finalize(
    const float* __restrict__ rowsum, const float* __restrict__ pos,
    float* __restrict__ out)
{
    const int tid = threadIdx.x;
    float acc = 0.f;
#pragma unroll
    for (int it = 0; it < NN / 256; ++it)
        acc += __builtin_amdgcn_logf(rowsum[tid + it * 256]);   // log2
    float pacc = 0.f;
#pragma unroll
    for (int it = 0; it < BB / 256; ++it)
        pacc += pos[tid + it * 256];

#pragma unroll
    for (int off = 32; off > 0; off >>= 1) {
        acc  += __shfl_xor(acc,  off);
        pacc += __shfl_xor(pacc, off);
    }
    __shared__ float sa[4], sp[4];
    const int wave = tid >> 6;
    if ((tid & 63) == 0) { sa[wave] = acc; sp[wave] = pacc; }
    __syncthreads();
    if (tid == 0) {
        const float lntot = (sa[0] + sa[1] + sa[2] + sa[3]) * 0.6931471805599453f;
        const float ptot  = sp[0] + sp[1] + sp[2] + sp[3];
        out[0] = (lntot - 4.0f * ptot) * (1.0f / (float)NN);
    }
}

// ---------------- Launch ------------------------------------------------------
extern "C" void kernel_launch(void* const* d_in, const int* in_sizes, int n_in,
                              void* d_out, int out_size, void* d_ws, size_t ws_size,
                              hipStream_t stream) {
    const float* zi = (const float*)d_in[0];
    const float* zj = (const float*)d_in[1];
    float* out = (float*)d_out;

    _Float16* Zf = (_Float16*)d_ws;                                 // 4 MB
    float* rowsum = (float*)((char*)d_ws + (size_t)NN * DD * 2);    // 32 KB
    float* pos = rowsum + NN;                                       // 16 KB

    nt_normalize<<<BB / 32, 256, 0, stream>>>(zi, zj, Zf, pos, rowsum);
    nt_simexp<<<NBLK, 256, 0, stream>>>((const _Float16*)Zf, rowsum);
    nt_finalize<<<1, 256, 0, stream>>>(rowsum, pos, out);
}

// Round 10
// 101.696 us; speedup vs baseline: 1.5753x; 1.5753x over previous
//
#include <hip/hip_runtime.h>
#include <hip/hip_bf16.h>

// NT-Xent (SimCLR) loss, B=4096, D=256, N=8192, T=0.5.
// loss = [ sum_i log(sum_{j!=i} exp(sim_ij * 2)) - 4 * sum_{i<B} pos_i ] / N
// sim symmetric: upper-triangle tiles. Strip-chunk blocks: (row-strip of 128
// rows) x (2 column-tiles of 128). 1056 blocks (=8*132), 512 thr / 8 waves,
// ONE job per wave = 128 rows x 32 cols -> acc[4] = 64 AGPR (no spill; r9's
// 128-acc version spilled: WRITE_SIZE 50 MB). A-strip staged once in LDS
// (64 KB, fragment order, linear DMA); B streamed coalesced from L2.
// L2 traffic ~200 MB vs 532 MB for all previous ~34 us structures.

constexpr int BB = 4096;                 // batch
constexpr int NN = 8192;                 // 2*batch
constexpr int DD = 256;                  // feature dim
constexpr int TS = 128;                  // tile edge
constexpr int NT = NN / TS;              // 64 tile rows/cols
constexpr int NBLK = 1056;               // sum over rt of ceil((64-rt)/2)
constexpr int KSTEPS = DD / 16;          // 16 MFMA k-steps

typedef _Float16 half4v __attribute__((ext_vector_type(4)));
typedef _Float16 half8v __attribute__((ext_vector_type(8)));
typedef float floatx16 __attribute__((ext_vector_type(16)));

// ---------------- Kernel 1: normalize -> fragment-ordered f16 (r8 verbatim) -
// Zf granule (g*16+ks)*64 + lm + 32*lh holds halfs [16ks+8lh, +8) of row
// 32g+lm. A wave's fragment load = 1 KB contiguous.
__global__ __launch_bounds__(256) void nt_normalize(
    const float* __restrict__ zi, const float* __restrict__ zj,
    _Float16* __restrict__ Zf, float* __restrict__ pos,
    float* __restrict__ rowsum)
{
    __shared__ _Float16 sZ[2][16 * 64 * 8];   // 2 groups x 1024 granules = 32 KB
    const int tid = threadIdx.x;
    const int pr  = tid >> 3;     // row within group, 0..31
    const int sub = tid & 7;      // 8 threads per row
    const int p   = blockIdx.x * 32 + pr;     // pair index, < BB

    if (blockIdx.x < 32) rowsum[blockIdx.x * 256 + tid] = 0.f;

    const float4* ai = (const float4*)(zi + (size_t)p * DD);
    const float4* bj = (const float4*)(zj + (size_t)p * DD);
    float4 av[8], bv[8];
    float ssi = 0.f, ssj = 0.f, dd = 0.f;
#pragma unroll
    for (int t = 0; t < 8; ++t) {
        av[t] = ai[sub + 8 * t];
        bv[t] = bj[sub + 8 * t];
        ssi += av[t].x*av[t].x + av[t].y*av[t].y + av[t].z*av[t].z + av[t].w*av[t].w;
        ssj += bv[t].x*bv[t].x + bv[t].y*bv[t].y + bv[t].z*bv[t].z + bv[t].w*bv[t].w;
        dd  += av[t].x*bv[t].x + av[t].y*bv[t].y + av[t].z*bv[t].z + av[t].w*bv[t].w;
    }
#pragma unroll
    for (int off = 1; off < 8; off <<= 1) {
        ssi += __shfl_xor(ssi, off);
        ssj += __shfl_xor(ssj, off);
        dd  += __shfl_xor(dd,  off);
    }
    const float invi = rsqrtf(ssi);
    const float invj = rsqrtf(ssj);
    if (sub == 0) pos[p] = dd * invi * invj;

#pragma unroll
    for (int t = 0; t < 8; ++t) {
        const int gi = (2 * t + (sub >> 2)) * 64 + pr + 32 * ((sub >> 1) & 1);
        const int wo = 4 * (sub & 1);
        half4v hi, hj;
        hi.x = (_Float16)(av[t].x * invi); hi.y = (_Float16)(av[t].y * invi);
        hi.z = (_Float16)(av[t].z * invi); hi.w = (_Float16)(av[t].w * invi);
        hj.x = (_Float16)(bv[t].x * invj); hj.y = (_Float16)(bv[t].y * invj);
        hj.z = (_Float16)(bv[t].z * invj); hj.w = (_Float16)(bv[t].w * invj);
        *(half4v*)&sZ[0][gi * 8 + wo] = hi;
        *(half4v*)&sZ[1][gi * 8 + wo] = hj;
    }
    __syncthreads();

    float4* Zf4 = (float4*)Zf;
    const float4* s0 = (const float4*)sZ[0];
    const float4* s1 = (const float4*)sZ[1];
    const size_t gbi = (size_t)blockIdx.x * 1024;
    const size_t gbj = (size_t)(128 + blockIdx.x) * 1024;
#pragma unroll
    for (int it = 0; it < 4; ++it) {
        Zf4[gbi + tid + it * 256] = s0[tid + it * 256];
        Zf4[gbj + tid + it * 256] = s1[tid + it * 256];
    }
}

// DPP half-wave reduce: lane31 = sum(lanes 0..31), lane63 = sum(lanes 32..63).
__device__ __forceinline__ float half_sums(float x) {
    int t;
    t = __builtin_amdgcn_update_dpp(0, __builtin_bit_cast(int, x), 0x111, 0xf, 0xf, false);
    x += __builtin_bit_cast(float, t);
    t = __builtin_amdgcn_update_dpp(0, __builtin_bit_cast(int, x), 0x112, 0xf, 0xf, false);
    x += __builtin_bit_cast(float, t);
    t = __builtin_amdgcn_update_dpp(0, __builtin_bit_cast(int, x), 0x114, 0xf, 0xf, false);
    x += __builtin_bit_cast(float, t);
    t = __builtin_amdgcn_update_dpp(0, __builtin_bit_cast(int, x), 0x118, 0xf, 0xf, false);
    x += __builtin_bit_cast(float, t);
    t = __builtin_amdgcn_update_dpp(0, __builtin_bit_cast(int, x), 0x142, 0xa, 0xf, false);
    x += __builtin_bit_cast(float, t);
    return x;
}

// ---------------- Kernel 2: strip-chunk upper-tri sim + exp + row/col sums --
// Grid: 1056 blocks x 512 thr (8 waves). Block = (rt, {ct0, ct0+1}).
// A-strip (128 rows, fragment order) staged once into LDS (64 KB).
// Wave w -> tile tx = w>>2 (idle if tx >= ntiles), col-slice jit = w&3:
// job = 128 rows x 32 cols, acc[4] (64 AGPR). Per k-step: 4 ds_read_b128 +
// 1 coalesced global B + 4 MFMA. 2 barriers per block; no k-loop barriers.
__global__ __launch_bounds__(512, 2) void nt_simexp(
    const _Float16* __restrict__ Zf, float* __restrict__ rowsum)
{
    __shared__ alignas(16) _Float16 sA[4 * 16 * 64 * 8];   // 64 KB
    __shared__ float rowaccA[TS];                          // 512 B

    // Bijective XCD swizzle (1056 % 8 == 0).
    const int bid = (blockIdx.x & 7) * (NBLK / 8) + (blockIdx.x >> 3);

    // Map bid -> (rt, chunk of 2 tiles). Scalar loop, <=64 iters, SALU only.
    int rt = 0, rem = bid;
    while (true) {
        const int nch = (NT - rt + 1) >> 1;
        if (rem < nch) break;
        rem -= nch; ++rt;
    }
    const int ct0 = rt + rem * 2;
    const int ntiles = min(2, NT - ct0);

    const int tid = threadIdx.x;
    const int wave = tid >> 6;
    const int lane = tid & 63;
    const int lm = lane & 31;
    const int lh = lane >> 5;

    // Stage A-strip: wave w stages group w>>1, ks-half w&1 (8 x 1 KB DMA).
    // Linear source (fragment order), linear dest; lane term = lane*16B both.
    {
        const int g  = wave >> 1;
        const int kh = (wave & 1) * 8;
        const _Float16* src = Zf + (((size_t)(rt * 4 + g) * 16 + kh) * 64 + lane) * 8;
        _Float16* dst = sA + ((size_t)(g * 16 + kh) * 64) * 8;   // uniform base
#pragma unroll
        for (int k2 = 0; k2 < 8; ++k2) {
            __builtin_amdgcn_global_load_lds(
                (const __attribute__((address_space(1))) unsigned int*)(src + k2 * 512),
                (__attribute__((address_space(3))) unsigned int*)(dst + k2 * 512),
                16, 0, 0);
        }
    }
    if (tid < TS) rowaccA[tid] = 0.f;
    __syncthreads();                 // DMA drained (implicit vmcnt), zero done

    const int tx  = wave >> 2;       // tile within chunk
    const int jit = wave & 3;        // 32-col slice within tile

    if (tx < ntiles) {
        const int ct = ct0 + tx;
        const bool dj = (ct == rt);
        const int cb = ct * TS + jit * 32;    // global col base

        // B fragment stream: col-group ct*4+jit, r8-verified coalesced layout.
        const half8v* pb = (const half8v*)Zf + (size_t)(ct * 4 + jit) * 1024 + lane;
        const half8v* sAf = (const half8v*)sA;

        floatx16 acc0, acc1, acc2, acc3;
#pragma unroll
        for (int r = 0; r < 16; ++r) { acc0[r] = 0.f; acc1[r] = 0.f; acc2[r] = 0.f; acc3[r] = 0.f; }

        half8v fb = pb[0];
#pragma unroll
        for (int ks = 0; ks < KSTEPS; ++ks) {
            half8v nfb = fb;
            if (ks + 1 < KSTEPS) nfb = pb[(ks + 1) * 64];
            half8v fa0 = sAf[(0 * 16 + ks) * 64 + lane];
            half8v fa1 = sAf[(1 * 16 + ks) * 64 + lane];
            half8v fa2 = sAf[(2 * 16 + ks) * 64 + lane];
            half8v fa3 = sAf[(3 * 16 + ks) * 64 + lane];
            acc0 = __builtin_amdgcn_mfma_f32_32x32x16_f16(fa0, fb, acc0, 0, 0, 0);
            acc1 = __builtin_amdgcn_mfma_f32_32x32x16_f16(fa1, fb, acc1, 0, 0, 0);
            acc2 = __builtin_amdgcn_mfma_f32_32x32x16_f16(fa2, fb, acc2, 0, 0, 0);
            acc3 = __builtin_amdgcn_mfma_f32_32x32x16_f16(fa3, fb, acc3, 0, 0, 0);
            fb = nfb;
        }

        // Epilogue (r9-validated math, single col-stream). Element (g, r):
        // strip row = 32g + mrow, tile col = jit*32 + lm.
        const float KEXP = 2.0f * 1.44269504088896340736f;
        float ebs = 0.f;
#pragma unroll
        for (int g = 0; g < 4; ++g) {
            const floatx16& ac = (g == 0) ? acc0 : (g == 1) ? acc1 : (g == 2) ? acc2 : acc3;
#pragma unroll
            for (int r = 0; r < 16; ++r) {
                const int mrow = (r & 3) + 8 * (r >> 2) + 4 * lh;
                float e = __builtin_amdgcn_exp2f(ac[r] * KEXP);
                if (dj && (32 * g + mrow == jit * 32 + lm)) e = 0.f;  // diagonal
                ebs += e;
                if (!dj) {   // A-side (strip-row) sums via DPP reduce
                    float s2 = half_sums(e);             // lanes 31/63
                    if (lm == 31)
                        atomicAdd(&rowaccA[32 * g + mrow], s2);   // ds_add
                }
            }
        }
        // B-side (col) sums: lane halves cover complementary row sets.
        ebs += __shfl_xor(ebs, 32);
        if (lane < 32)
            atomicAdd(&rowsum[cb + lm], ebs);
    }

    __syncthreads();
    if (tid < TS) atomicAdd(&rowsum[rt * TS + tid], rowaccA[tid]);
}

// ---------------- Kernel 3: finalize ----------------------------------------
__global__ __launch_bounds__(256) void nt_finalize(
    const float* __restrict__ rowsum, const float* __restrict__ pos,
    float* __restrict__ out)
{
    const int tid = threadIdx.x;
    float acc = 0.f;
#pragma unroll
    for (int it = 0; it < NN / 256; ++it)
        acc += __builtin_amdgcn_logf(rowsum[tid + it * 256]);   // log2
    float pacc = 0.f;
#pragma unroll
    for (int it = 0; it < BB / 256; ++it)
        pacc += pos[tid + it * 256];

#pragma unroll
    for (int off = 32; off > 0; off >>= 1) {
        acc  += __shfl_xor(acc,  off);
        pacc += __shfl_xor(pacc, off);
    }
    __shared__ float sa[4], sp[4];
    const int wave = tid >> 6;
    if ((tid & 63) == 0) { sa[wave] = acc; sp[wave] = pacc; }
    __syncthreads();
    if (tid == 0) {
        const float lntot = (sa[0] + sa[1] + sa[2] + sa[3]) * 0.6931471805599453f;
        const float ptot  = sp[0] + sp[1] + sp[2] + sp[3];
        out[0] = (lntot - 4.0f * ptot) * (1.0f / (float)NN);
    }
}

// ---------------- Launch ------------------------------------------------------
extern "C" void kernel_launch(void* const* d_in, const int* in_sizes, int n_in,
                              void* d_out, int out_size, void* d_ws, size_t ws_size,
                              hipStream_t stream) {
    const float* zi = (const float*)d_in[0];
    const float* zj = (const float*)d_in[1];
    float* out = (float*)d_out;

    _Float16* Zf = (_Float16*)d_ws;                                 // 4 MB
    float* rowsum = (float*)((char*)d_ws + (size_t)NN * DD * 2);    // 32 KB
    float* pos = rowsum + NN;                                       // 16 KB

    nt_normalize<<<BB / 32, 256, 0, stream>>>(zi, zj, Zf, pos, rowsum);
    nt_simexp<<<NBLK, 512, 0, stream>>>((const _Float16*)Zf, rowsum);
    nt_finalize<<<1, 256, 0, stream>>>(rowsum, pos, out);
}